// Round 5
// baseline (543.140 us; speedup 1.0000x reference)
//
#include <hip/hip_runtime.h>

#define B_    128
#define H_    256
#define WI_   256
#define CIN   8
#define COUT  8
#define CT    32
#define SS    64
#define RST   (WI_*CIN)    // floats per input row
#define OST   (WI_*COUT)   // floats per output row

// thread = (column, cout). Rolling 3-accumulator over input rows with
// explicit 1-step ping-pong prefetch (named float4 regs, no arrays).

__global__ __launch_bounds__(256, 3)
void conv_aconnect_kernel(const float* __restrict__ X,
                          const float* __restrict__ Wt,
                          const float* __restrict__ bias,
                          const float* __restrict__ Werr,
                          const float* __restrict__ Berr,
                          float* __restrict__ out)
{
    const int tid  = threadIdx.x;
    const int o    = tid & 7;            // cout
    const int cl   = tid >> 3;           // local column
    const int colg = blockIdx.x * CT + cl;
    const int rs   = blockIdx.y * SS;
    const int b    = blockIdx.z;

    // per-thread noisy weights (72 regs, constant-indexed everywhere)
    float w[3][3][CIN];
    {
        const float* we = Werr + (size_t)b * 576;
        #pragma unroll
        for (int kh = 0; kh < 3; ++kh)
            #pragma unroll
            for (int kw = 0; kw < 3; ++kw)
                #pragma unroll
                for (int ci = 0; ci < CIN; ++ci) {
                    const int idx = ((kh*3 + kw)*CIN + ci)*COUT + o;
                    w[kh][kw][ci] = Wt[idx] * we[idx];
                }
    }
    if (colg == 0) {
        #pragma unroll
        for (int kh = 0; kh < 3; ++kh)
            #pragma unroll
            for (int ci = 0; ci < CIN; ++ci) w[kh][0][ci] = 0.f;
    }
    if (colg == WI_ - 1) {
        #pragma unroll
        for (int kh = 0; kh < 3; ++kh)
            #pragma unroll
            for (int ci = 0; ci < CIN; ++ci) w[kh][2][ci] = 0.f;
    }
    const float biasv = bias[o] * Berr[(size_t)b * COUT + o];

    const float* __restrict__ xb = X   + (size_t)b * H_ * RST;  // uniform (SGPR base)
    float*       __restrict__ ob = out + (size_t)b * H_ * OST;  // uniform

    const int cL = (colg > 0)       ? colg - 1 : 0;
    const int cR = (colg < WI_ - 1) ? colg + 1 : WI_ - 1;

    const int rowFirst = (rs > 0) ? rs - 1 : rs;
    int vL = cL   * CIN + rowFirst * RST;   // 32-bit element offsets
    int vC = colg * CIN + rowFirst * RST;
    int vR = cR   * CIN + rowFirst * RST;

    float4 A0, A1, A2, A3, A4, A5, B0, B1, B2, B3, B4, B5;

    if (rs > 0) {                     // buffer A <- input row rs-1
        A0 = *(const float4*)(xb + vL); A1 = *(const float4*)(xb + vL + 4);
        A2 = *(const float4*)(xb + vC); A3 = *(const float4*)(xb + vC + 4);
        A4 = *(const float4*)(xb + vR); A5 = *(const float4*)(xb + vR + 4);
        vL += RST; vC += RST; vR += RST;
    } else {                          // top strip: row -1 is zero padding
        const float4 z = make_float4(0.f, 0.f, 0.f, 0.f);
        A0 = z; A1 = z; A2 = z; A3 = z; A4 = z; A5 = z;
    }
    int nextRow = rs;                 // next input row to prefetch (uniform)

    float acc0 = 0.f, acc1 = 0.f, acc2 = 0.f;
    int so = (rs * WI_ + colg) * COUT + o;    // first store offset (out row rs)

#define FMA8(ACC, KH, KW, LO, HI)                                             \
    ACC += LO.x * w[KH][KW][0]; ACC += LO.y * w[KH][KW][1];                   \
    ACC += LO.z * w[KH][KW][2]; ACC += LO.w * w[KH][KW][3];                   \
    ACC += HI.x * w[KH][KW][4]; ACC += HI.y * w[KH][KW][5];                   \
    ACC += HI.z * w[KH][KW][6]; ACC += HI.w * w[KH][KW][7]

#define COMP(V0,V1,V2,V3,V4,V5) do {                                          \
    acc2 = 0.f;                                                               \
    FMA8(acc0, 2, 0, V0, V1); FMA8(acc1, 1, 0, V0, V1); FMA8(acc2, 0, 0, V0, V1); \
    FMA8(acc0, 2, 1, V2, V3); FMA8(acc1, 1, 1, V2, V3); FMA8(acc2, 0, 1, V2, V3); \
    FMA8(acc0, 2, 2, V4, V5); FMA8(acc1, 1, 2, V4, V5); FMA8(acc2, 0, 2, V4, V5); \
} while (0)

// issue next row's loads into P*, then compute current row from C*
#define STEP(C0,C1,C2,C3,C4,C5, P0,P1,P2,P3,P4,P5, DOSTORE) do {              \
    P0 = *(const float4*)(xb + vL); P1 = *(const float4*)(xb + vL + 4);       \
    P2 = *(const float4*)(xb + vC); P3 = *(const float4*)(xb + vC + 4);       \
    P4 = *(const float4*)(xb + vR); P5 = *(const float4*)(xb + vR + 4);       \
    { const int inc_ = (nextRow < H_ - 1) ? RST : 0;                          \
      vL += inc_; vC += inc_; vR += inc_; ++nextRow; }                        \
    COMP(C0,C1,C2,C3,C4,C5);                                                  \
    if (DOSTORE) { ob[so] = acc0 + biasv; so += OST; }                        \
    acc0 = acc1; acc1 = acc2;                                                 \
} while (0)

    // step 0: compute row rs-1 (A), prefetch row rs   (B). no store.
    STEP(A0,A1,A2,A3,A4,A5, B0,B1,B2,B3,B4,B5, 0);
    // step 1: compute row rs   (B), prefetch row rs+1 (A). no store.
    STEP(B0,B1,B2,B3,B4,B5, A0,A1,A2,A3,A4,A5, 0);

    // steps 2..63: 31 x (compute A / compute B), each stores one out row
    #pragma unroll 1
    for (int it = 0; it < 31; ++it) {
        STEP(A0,A1,A2,A3,A4,A5, B0,B1,B2,B3,B4,B5, 1);
        STEP(B0,B1,B2,B3,B4,B5, A0,A1,A2,A3,A4,A5, 1);
    }
    // step 64: compute row rs+63 (A), store out rs+62, prefetch row rs+64
    // (clamped to row 255 for the bottom strip; that data is never consumed)
    STEP(A0,A1,A2,A3,A4,A5, B0,B1,B2,B3,B4,B5, 1);

    // step 65: out row rs+63. Non-bottom strips: add w[2] * input row rs+64.
    // Bottom strip: padded row contributes zero -> acc0 already complete.
    if (rs + SS < H_) {
        COMP(B0,B1,B2,B3,B4,B5);
    }
    ob[so] = acc0 + biasv;

#undef STEP
#undef COMP
#undef FMA8
}

extern "C" void kernel_launch(void* const* d_in, const int* in_sizes, int n_in,
                              void* d_out, int out_size, void* d_ws, size_t ws_size,
                              hipStream_t stream) {
    const float* X    = (const float*)d_in[0];
    const float* Wt   = (const float*)d_in[1];
    const float* bias = (const float*)d_in[2];
    const float* Werr = (const float*)d_in[3];
    const float* Berr = (const float*)d_in[4];
    float* out = (float*)d_out;

    dim3 grid(WI_ / CT, H_ / SS, B_);
    conv_aconnect_kernel<<<grid, 256, 0, stream>>>(X, Wt, bias, Werr, Berr, out);
}

// Round 6
// 170.205 us; speedup vs baseline: 3.1911x; 3.1911x over previous
//
#include <hip/hip_runtime.h>
#include <hip/hip_bf16.h>

#define B_    128
#define H_    256
#define WI_   256
#define CIN   8
#define COUT  8
#define SS    64
#define RST   (WI_*CIN)     // 2048 f32 per input row
#define OST   (WI_*COUT)    // 2048 f32 per output row

typedef __attribute__((ext_vector_type(8))) short bh8;   // 8 bf16 (MFMA A/B frag)
typedef __attribute__((ext_vector_type(4))) float f4;    // MFMA C/D frag

static __device__ __forceinline__ unsigned short f2bf(float f) {
    union { __hip_bfloat16 h; unsigned short u; } c;
    c.h = __float2bfloat16(f);
    return c.u;
}

// pack 8 f32 -> 8 bf16 frag, then AND-mask the 4 dwords (0 or ~0) — NaN-safe zeroing
static __device__ __forceinline__ bh8 pack_mask(float4 lo, float4 hi, unsigned m) {
    union { bh8 v; unsigned short u[8]; unsigned w[4]; } r;
    r.u[0]=f2bf(lo.x); r.u[1]=f2bf(lo.y); r.u[2]=f2bf(lo.z); r.u[3]=f2bf(lo.w);
    r.u[4]=f2bf(hi.x); r.u[5]=f2bf(hi.y); r.u[6]=f2bf(hi.z); r.u[7]=f2bf(hi.w);
    r.w[0]&=m; r.w[1]&=m; r.w[2]&=m; r.w[3]&=m;
    return r.v;
}

// wave = 16-column output segment marching down SS rows.
// A(h') [16 pix x K32] : lane: row(pixel)=lane&15, k=(lane>>4)*8+j -> X[h'][w0+(lane&15)+g-1][0..8]
// B[kh] [K32 x N16]    : lane: col(cout)=lane&15, k-group g -> memW[kh][kw=g][ci=j][cout]; k>=24,n>=8 zero
// D     [16 pix x 16]  : lane: cout=lane&15, pixel=(lane>>4)*4+reg
__global__ __launch_bounds__(256, 4)
void conv_mfma_kernel(const float* __restrict__ X,
                      const float* __restrict__ Wt,
                      const float* __restrict__ bias,
                      const float* __restrict__ Werr,
                      const float* __restrict__ Berr,
                      float* __restrict__ out)
{
    __shared__ float wlds[576];           // noisy weights, transposed [khkw][cout][cin]
    const int tid = threadIdx.x;
    const int b   = blockIdx.z;
    const int rs  = blockIdx.y * SS;

    {   // stage transposed noisy weights
        const float* we = Werr + (size_t)b * 576;
        for (int i = tid; i < 576; i += 256) {
            const int khkw = i >> 6, ci = (i >> 3) & 7, co = i & 7;
            wlds[(khkw * 8 + co) * 8 + ci] = Wt[i] * we[i];
        }
    }
    __syncthreads();

    const int lane = tid & 63, wid = tid >> 6;
    const int w0 = blockIdx.x * 64 + wid * 16;
    const int n  = lane & 15;             // B/D col (cout) AND A row (pixel)
    const int g  = lane >> 4;             // k-group / store pixel-group

    // ---- B fragments (one per kh), zero-padded for k>=24 and n>=8 ----
    bh8 Bf0, Bf1, Bf2;
    {
        const float4 z4 = make_float4(0.f, 0.f, 0.f, 0.f);
        #pragma unroll
        for (int kh = 0; kh < 3; ++kh) {
            float4 lo = z4, hi = z4;
            if (n < 8 && g < 3) {
                const float* p = &wlds[((kh * 3 + g) * 8 + n) * 8];
                lo = *(const float4*)p;
                hi = *(const float4*)(p + 4);
            }
            const bh8 f = pack_mask(lo, hi, 0xffffffffu);
            if (kh == 0) Bf0 = f; else if (kh == 1) Bf1 = f; else Bf2 = f;
        }
    }

    const float biasv = (n < 8) ? bias[n] * Berr[(size_t)b * COUT + n] : 0.f;
    const f4 biasF = {biasv, biasv, biasv, biasv};

    // ---- A addressing: per-lane column, clamped + bitmasked at frag build ----
    const int col = w0 + n + g - 1;
    const unsigned amask = ((unsigned)col < (unsigned)WI_ && g < 3) ? 0xffffffffu : 0u;
    const int colc = col < 0 ? 0 : (col > WI_ - 1 ? WI_ - 1 : col);
    const float* __restrict__ xb = X + (size_t)b * H_ * RST;
    int voff = (rs > 0 ? rs - 1 : rs) * RST + colc * CIN;

    float4 X0, X1, Y0, Y1;
    if (rs > 0) {                         // buffer X <- input row rs-1
        X0 = *(const float4*)(xb + voff);
        X1 = *(const float4*)(xb + voff + 4);
        voff += RST;
    } else {                              // top: row -1 is zero padding
        X0 = make_float4(0.f, 0.f, 0.f, 0.f); X1 = X0;
    }
    int nextRow = rs;                     // uniform: row voff points at

    float* __restrict__ ob = out + (size_t)b * H_ * OST;
    int soff = (rs * WI_ + w0 + g * 4) * COUT + n;   // first store: out row rs

    // live partials between steps: P1 = out h'-1 (has kh0+kh1), P2 = out h' (has kh0)
    f4 P1 = biasF, P2 = biasF;

#define STEP(C0, C1, N0, N1, DS) do {                                          \
    N0 = *(const float4*)(xb + voff);                                          \
    N1 = *(const float4*)(xb + voff + 4);                                      \
    { const int inc_ = (nextRow < H_ - 1) ? RST : 0; voff += inc_; ++nextRow; }\
    const bh8 af = pack_mask(C0, C1, amask);                                   \
    const f4 done = __builtin_amdgcn_mfma_f32_16x16x32_bf16(af, Bf2, P1, 0,0,0);\
    P1 = __builtin_amdgcn_mfma_f32_16x16x32_bf16(af, Bf1, P2, 0,0,0);          \
    P2 = __builtin_amdgcn_mfma_f32_16x16x32_bf16(af, Bf0, biasF, 0,0,0);       \
    if (DS) {                                                                  \
        if (n < 8) {                                                           \
            float* p = ob + soff;                                              \
            p[0]  = done[0]; p[8]  = done[1];                                  \
            p[16] = done[2]; p[24] = done[3];                                  \
        }                                                                      \
        soff += OST;                                                           \
    }                                                                          \
} while (0)

    STEP(X0, X1, Y0, Y1, 0);              // h' = rs-1 : discard
    STEP(Y0, Y1, X0, X1, 0);              // h' = rs   : discard

    #pragma unroll 1
    for (int it = 0; it < 31; ++it) {     // h' = rs+1 .. rs+62 : store out rs..rs+61
        STEP(X0, X1, Y0, Y1, 1);
        STEP(Y0, Y1, X0, X1, 1);
    }
    STEP(X0, X1, Y0, Y1, 1);              // h' = rs+63 : store out rs+62; Y <- row rs+64

    // out row rs+63: needs kh=2 term from input row rs+64 (bottom strip: zero pad)
    if (rs + SS < H_) {
        const bh8 af = pack_mask(Y0, Y1, amask);
        P1 = __builtin_amdgcn_mfma_f32_16x16x32_bf16(af, Bf2, P1, 0, 0, 0);
    }
    if (n < 8) {
        float* p = ob + soff;
        p[0] = P1[0]; p[8] = P1[1]; p[16] = P1[2]; p[24] = P1[3];
    }
#undef STEP
}

extern "C" void kernel_launch(void* const* d_in, const int* in_sizes, int n_in,
                              void* d_out, int out_size, void* d_ws, size_t ws_size,
                              hipStream_t stream) {
    const float* X    = (const float*)d_in[0];
    const float* Wt   = (const float*)d_in[1];
    const float* bias = (const float*)d_in[2];
    const float* Werr = (const float*)d_in[3];
    const float* Berr = (const float*)d_in[4];
    float* out = (float*)d_out;

    dim3 grid(WI_ / 64, H_ / SS, B_);     // (4, 4, 128)
    conv_mfma_kernel<<<grid, 256, 0, stream>>>(X, Wt, bias, Werr, Berr, out);
}

// Round 7
// 121.089 us; speedup vs baseline: 4.4854x; 1.4056x over previous
//
#include <hip/hip_runtime.h>
#include <hip/hip_bf16.h>

#define B_    128
#define H_    256
#define WI_   256
#define CIN   8
#define COUT  8
#define SS    64
#define RST   (WI_*CIN)     // 2048 f32 per input row
#define OST   (WI_*COUT)    // 2048 f32 per output row

typedef __attribute__((ext_vector_type(8))) short bh8;   // 8 bf16 (MFMA A/B frag)
typedef __attribute__((ext_vector_type(4))) float f4;    // MFMA C/D frag

static __device__ __forceinline__ unsigned short f2bf(float f) {
    union { __hip_bfloat16 h; unsigned short u; } c;
    c.h = __float2bfloat16(f);
    return c.u;
}

static __device__ __forceinline__ bh8 pack_mask(float4 lo, float4 hi, unsigned m) {
    union { bh8 v; unsigned short u[8]; unsigned w[4]; } r;
    r.u[0]=f2bf(lo.x); r.u[1]=f2bf(lo.y); r.u[2]=f2bf(lo.z); r.u[3]=f2bf(lo.w);
    r.u[4]=f2bf(hi.x); r.u[5]=f2bf(hi.y); r.u[6]=f2bf(hi.z); r.u[7]=f2bf(hi.w);
    r.w[0]&=m; r.w[1]&=m; r.w[2]&=m; r.w[3]&=m;
    return r.v;
}

// wave = 16-column output segment marching down SS rows.
// MFMA: D = Wfrag(A, M=cout) x Xfrag(B, N=pixel) + C
//   Wfrag[kh]: lane m=lane&15 (cout, 8 real), g=lane>>4 -> kw=g (g<3), k_j=ci
//   Xfrag(h'): lane p=lane&15 (pixel), g=lane>>4 -> col=w0+p+g-1, k_j=ci
//   D: lane p=lane&15 (pixel), couts 4q..4q+3 where q=lane>>4 (q<2 real)
__global__ __launch_bounds__(256, 2)
void conv_mfma_kernel(const float* __restrict__ X,
                      const float* __restrict__ Wt,
                      const float* __restrict__ bias,
                      const float* __restrict__ Werr,
                      const float* __restrict__ Berr,
                      float* __restrict__ out)
{
    __shared__ float wlds[576];           // noisy weights, transposed [khkw][cout][cin]
    const int tid = threadIdx.x;
    const int b   = blockIdx.z;
    const int rs  = blockIdx.y * SS;

    {
        const float* we = Werr + (size_t)b * 576;
        for (int i = tid; i < 576; i += 256) {
            const int khkw = i >> 6, ci = (i >> 3) & 7, co = i & 7;
            wlds[(khkw * 8 + co) * 8 + ci] = Wt[i] * we[i];
        }
    }
    __syncthreads();

    const int lane = tid & 63, wid = tid >> 6;
    const int w0 = blockIdx.x * 64 + wid * 16;
    const int p  = lane & 15;             // pixel (B col / D col)  == cout slot for A
    const int g  = lane >> 4;             // k-group (kw) / D cout-quad index

    // ---- A fragments: weights, one per kh; zero for m>=8 or g==3 ----
    bh8 Wf0, Wf1, Wf2;
    {
        const float4 z4 = make_float4(0.f, 0.f, 0.f, 0.f);
        #pragma unroll
        for (int kh = 0; kh < 3; ++kh) {
            float4 lo = z4, hi = z4;
            if (p < 8 && g < 3) {         // m = p (lane&15) = cout slot
                const float* ptr = &wlds[((kh * 3 + g) * 8 + p) * 8];
                lo = *(const float4*)ptr;
                hi = *(const float4*)(ptr + 4);
            }
            const bh8 f = pack_mask(lo, hi, 0xffffffffu);
            if (kh == 0) Wf0 = f; else if (kh == 1) Wf1 = f; else Wf2 = f;
        }
    }

    // ---- bias fragment: D reg r holds cout 4*g+r (g<2) ----
    f4 biasF = {0.f, 0.f, 0.f, 0.f};
    if (g < 2) {
        #pragma unroll
        for (int r = 0; r < 4; ++r) {
            const int co = g * 4 + r;
            biasF[r] = bias[co] * Berr[(size_t)b * COUT + co];
        }
    }

    // ---- B (pixel) addressing: per-lane column, clamped + masked ----
    const int col = w0 + p + g - 1;
    const unsigned amask = ((unsigned)col < (unsigned)WI_ && g < 3) ? 0xffffffffu : 0u;
    const int colc = col < 0 ? 0 : (col > WI_ - 1 ? WI_ - 1 : col);
    const float* __restrict__ xb = X + (size_t)b * H_ * RST;
    int voff = (rs > 0 ? rs - 1 : rs) * RST + colc * CIN;

    float4 X0, X1, Y0, Y1;
    if (rs > 0) {
        X0 = *(const float4*)(xb + voff);
        X1 = *(const float4*)(xb + voff + 4);
        voff += RST;
    } else {
        X0 = make_float4(0.f, 0.f, 0.f, 0.f); X1 = X0;
    }
    int nextRow = rs;

    float* __restrict__ ob = out + (size_t)b * H_ * OST;
    int soff = (rs * WI_ + w0 + p) * COUT + g * 4;   // dense: lane p, cout-quad g

    f4 P1 = biasF, P2 = biasF;

#define STEP(C0, C1, N0, N1, DS) do {                                          \
    N0 = *(const float4*)(xb + voff);                                          \
    N1 = *(const float4*)(xb + voff + 4);                                      \
    { const int inc_ = (nextRow < H_ - 1) ? RST : 0; voff += inc_; ++nextRow; }\
    __builtin_amdgcn_sched_barrier(0);                                         \
    const bh8 xf = pack_mask(C0, C1, amask);                                   \
    const f4 done = __builtin_amdgcn_mfma_f32_16x16x32_bf16(Wf2, xf, P1, 0,0,0);\
    P1 = __builtin_amdgcn_mfma_f32_16x16x32_bf16(Wf1, xf, P2, 0,0,0);          \
    P2 = __builtin_amdgcn_mfma_f32_16x16x32_bf16(Wf0, xf, biasF, 0,0,0);       \
    if (DS) {                                                                  \
        if (lane < 32) *(float4*)(ob + soff) = *(const float4*)&done;          \
        soff += OST;                                                           \
    }                                                                          \
} while (0)

    STEP(X0, X1, Y0, Y1, 0);              // h' = rs-1 : discard
    STEP(Y0, Y1, X0, X1, 0);              // h' = rs   : discard

    #pragma unroll 1
    for (int it = 0; it < 31; ++it) {     // h' = rs+1 .. rs+62 : store out rs..rs+61
        STEP(X0, X1, Y0, Y1, 1);
        STEP(Y0, Y1, X0, X1, 1);
    }
    STEP(X0, X1, Y0, Y1, 1);              // h' = rs+63 : store out rs+62

    // out row rs+63: kh=2 term from input row rs+64 (bottom strip: zero pad)
    if (rs + SS < H_) {
        const bh8 xf = pack_mask(Y0, Y1, amask);
        P1 = __builtin_amdgcn_mfma_f32_16x16x32_bf16(Wf2, xf, P1, 0, 0, 0);
    }
    if (lane < 32) *(float4*)(ob + soff) = *(const float4*)&P1;

#undef STEP
}

extern "C" void kernel_launch(void* const* d_in, const int* in_sizes, int n_in,
                              void* d_out, int out_size, void* d_ws, size_t ws_size,
                              hipStream_t stream) {
    const float* X    = (const float*)d_in[0];
    const float* Wt   = (const float*)d_in[1];
    const float* bias = (const float*)d_in[2];
    const float* Werr = (const float*)d_in[3];
    const float* Berr = (const float*)d_in[4];
    float* out = (float*)d_out;

    dim3 grid(WI_ / 64, H_ / SS, B_);     // (4, 4, 128)
    conv_mfma_kernel<<<grid, 256, 0, stream>>>(X, Wt, bias, Werr, Berr, out);
}

// Round 8
// 100.244 us; speedup vs baseline: 5.4182x; 1.2080x over previous
//
#include <hip/hip_runtime.h>
#include <hip/hip_bf16.h>

#define B_    128
#define H_    256
#define WI_   256
#define CIN   8
#define COUT  8
#define SS    64
#define RST   (WI_*CIN)     // 2048 f32 per input row
#define OST   (WI_*COUT)    // 2048 f32 per output row

typedef __attribute__((ext_vector_type(8))) short bh8;   // 8 bf16 (MFMA A/B frag)
typedef __attribute__((ext_vector_type(4))) float f4;    // MFMA C/D frag

static __device__ __forceinline__ unsigned short f2bf(float f) {
    union { __hip_bfloat16 h; unsigned short u; } c;
    c.h = __float2bfloat16(f);
    return c.u;
}

static __device__ __forceinline__ bh8 pack_mask(float4 lo, float4 hi, unsigned m) {
    union { bh8 v; unsigned short u[8]; unsigned w[4]; } r;
    r.u[0]=f2bf(lo.x); r.u[1]=f2bf(lo.y); r.u[2]=f2bf(lo.z); r.u[3]=f2bf(lo.w);
    r.u[4]=f2bf(hi.x); r.u[5]=f2bf(hi.y); r.u[6]=f2bf(hi.z); r.u[7]=f2bf(hi.w);
    r.w[0]&=m; r.w[1]&=m; r.w[2]&=m; r.w[3]&=m;
    return r.v;
}

// wave = 16-column output segment marching down SS rows.
// MFMA: D = Wfrag(A, M=cout) x Xfrag(B, N=pixel) + C
//   Wfrag[kh]: lane m=lane&15 (cout, 8 real), g=lane>>4 -> kw=g (g<3), k_j=ci
//   Xfrag(h'): lane p=lane&15 (pixel), g=lane>>4 -> col=w0+p+g-1, k_j=ci
//   D: lane p=lane&15 (pixel), couts 4g..4g+3 (g<2 real) -> dense float4 store
// Depth-2 prefetch via 3 rotating named row buffers (R0,R1,R2).
__global__ __launch_bounds__(256, 2)
void conv_mfma_kernel(const float* __restrict__ X,
                      const float* __restrict__ Wt,
                      const float* __restrict__ bias,
                      const float* __restrict__ Werr,
                      const float* __restrict__ Berr,
                      float* __restrict__ out)
{
    __shared__ float wlds[576];           // noisy weights, transposed [khkw][cout][cin]
    const int tid = threadIdx.x;
    const int b   = blockIdx.z;
    const int rs  = blockIdx.y * SS;

    {
        const float* we = Werr + (size_t)b * 576;
        for (int i = tid; i < 576; i += 256) {
            const int khkw = i >> 6, ci = (i >> 3) & 7, co = i & 7;
            wlds[(khkw * 8 + co) * 8 + ci] = Wt[i] * we[i];
        }
    }
    __syncthreads();

    const int lane = tid & 63, wid = tid >> 6;
    const int w0 = blockIdx.x * 64 + wid * 16;
    const int p  = lane & 15;             // pixel (B col / D col); cout slot for A
    const int g  = lane >> 4;             // k-group (kw) / D cout-quad index

    // ---- A fragments: weights, one per kh; zero for m>=8 or g==3 ----
    bh8 Wf0, Wf1, Wf2;
    {
        const float4 z4 = make_float4(0.f, 0.f, 0.f, 0.f);
        #pragma unroll
        for (int kh = 0; kh < 3; ++kh) {
            float4 lo = z4, hi = z4;
            if (p < 8 && g < 3) {
                const float* ptr = &wlds[((kh * 3 + g) * 8 + p) * 8];
                lo = *(const float4*)ptr;
                hi = *(const float4*)(ptr + 4);
            }
            const bh8 f = pack_mask(lo, hi, 0xffffffffu);
            if (kh == 0) Wf0 = f; else if (kh == 1) Wf1 = f; else Wf2 = f;
        }
    }

    // ---- bias fragment: D reg r holds cout 4*g+r (g<2) ----
    f4 biasF = {0.f, 0.f, 0.f, 0.f};
    if (g < 2) {
        #pragma unroll
        for (int r = 0; r < 4; ++r) {
            const int co = g * 4 + r;
            biasF[r] = bias[co] * Berr[(size_t)b * COUT + co];
        }
    }

    // ---- X (pixel) addressing: per-lane column, clamped + masked ----
    const int col = w0 + p + g - 1;
    const unsigned amask = ((unsigned)col < (unsigned)WI_ && g < 3) ? 0xffffffffu : 0u;
    const int colc = col < 0 ? 0 : (col > WI_ - 1 ? WI_ - 1 : col);
    const float* __restrict__ xb = X + (size_t)b * H_ * RST;
    int voff = (rs > 0 ? rs - 1 : rs) * RST + colc * CIN;

    float4 R00, R01, R10, R11, R20, R21;
    if (rs > 0) {                          // R0 <- row rs-1
        R00 = *(const float4*)(xb + voff);
        R01 = *(const float4*)(xb + voff + 4);
        voff += RST;
    } else {                               // top strip: zero-pad row
        R00 = make_float4(0.f, 0.f, 0.f, 0.f); R01 = R00;
    }
    R10 = *(const float4*)(xb + voff);     // R1 <- row rs
    R11 = *(const float4*)(xb + voff + 4);
    voff += RST;
    int nextRow = rs + 1;                  // uniform: row voff points at

    float* __restrict__ ob = out + (size_t)b * H_ * OST;
    int soff = (rs * WI_ + w0 + p) * COUT + g * 4;   // dense: lane p, cout-quad g

    f4 P1 = biasF, P2 = biasF;

// load next row into N*, compute current row from C*
#define STEP(C0, C1, N0, N1, DS) do {                                          \
    N0 = *(const float4*)(xb + voff);                                          \
    N1 = *(const float4*)(xb + voff + 4);                                      \
    { const int inc_ = (nextRow < H_ - 1) ? RST : 0; voff += inc_; ++nextRow; }\
    __builtin_amdgcn_sched_barrier(0);                                         \
    const bh8 xf = pack_mask(C0, C1, amask);                                   \
    const f4 done = __builtin_amdgcn_mfma_f32_16x16x32_bf16(Wf2, xf, P1, 0,0,0);\
    P1 = __builtin_amdgcn_mfma_f32_16x16x32_bf16(Wf1, xf, P2, 0,0,0);          \
    P2 = __builtin_amdgcn_mfma_f32_16x16x32_bf16(Wf0, xf, biasF, 0,0,0);       \
    if (DS) {                                                                  \
        if (lane < 32)                                                         \
            __builtin_nontemporal_store(done, (f4*)(ob + soff));               \
        soff += OST;                                                           \
    }                                                                          \
} while (0)

    // s=0: compute row rs-1 (R0), load row rs+1 -> R2. no store.
    STEP(R00, R01, R20, R21, 0);
    // s=1: compute row rs (R1), load row rs+2 -> R0. no store.
    STEP(R10, R11, R00, R01, 0);

    // s=2..64: h' = rs+1 .. rs+63, store out rows rs .. rs+62
    #pragma unroll 1
    for (int it = 0; it < 21; ++it) {
        STEP(R20, R21, R10, R11, 1);       // s%3==2
        STEP(R00, R01, R20, R21, 1);       // s%3==0
        STEP(R10, R11, R00, R01, 1);       // s%3==1
    }

    // out row rs+63: kh=2 term from input row rs+64 (in R2); bottom strip: zero pad
    if (rs + SS < H_) {
        const bh8 xf = pack_mask(R20, R21, amask);
        P1 = __builtin_amdgcn_mfma_f32_16x16x32_bf16(Wf2, xf, P1, 0, 0, 0);
    }
    if (lane < 32)
        __builtin_nontemporal_store(P1, (f4*)(ob + soff));

#undef STEP
}

extern "C" void kernel_launch(void* const* d_in, const int* in_sizes, int n_in,
                              void* d_out, int out_size, void* d_ws, size_t ws_size,
                              hipStream_t stream) {
    const float* X    = (const float*)d_in[0];
    const float* Wt   = (const float*)d_in[1];
    const float* bias = (const float*)d_in[2];
    const float* Werr = (const float*)d_in[3];
    const float* Berr = (const float*)d_in[4];
    float* out = (float*)d_out;

    dim3 grid(WI_ / 64, H_ / SS, B_);     // (4, 4, 128)
    conv_mfma_kernel<<<grid, 256, 0, stream>>>(X, Wt, bias, Werr, Berr, out);
}